// Round 1
// baseline (268.356 us; speedup 1.0000x reference)
//
#include <hip/hip_runtime.h>

// Problem constants (match reference setup_inputs()).
constexpr int B = 4, C = 8, H = 160, W = 160, D = 160, NPER = 100000;
constexpr int TOTAL = NPER * B * C;   // 3,200,000 output elements

__global__ __launch_bounds__(256) void og_proj_kernel(
    const float* __restrict__ img,   // [B, C, H, W, D]
    const float* __restrict__ gf,    // [B*NPER, 3]
    const int*   __restrict__ dimp,  // [1] image_dim (int or float bits)
    float*       __restrict__ out)   // [NPER, B*C]
{
    int o = blockIdx.x * 256 + threadIdx.x;
    if (o >= TOTAL) return;

    int j  = o >> 5;        // point index within image
    int bc = o & 31;
    int b  = bc >> 3;
    int c  = bc & 7;

    // image_dim may arrive as int32 or float32 bits; disambiguate.
    int iv = dimp[0];
    float image_dim = (iv > 0 && iv < 1000000) ? (float)iv : __int_as_float(iv);
    float factor = image_dim / (float)H;   // reference uses image_dim/H for all axes

    size_t p = (size_t)b * NPER + (size_t)j;
    float x = gf[p * 3 + 0] / factor;
    float y = gf[p * 3 + 1] / factor;
    float z = gf[p * 3 + 2] / factor;

    // bounds(v, size): lo = min(floor(v), size-1), hi = min(ceil(v), size-1)
    float x1f = fminf(floorf(x), (float)(H - 1));
    float x2f = fminf(ceilf(x),  (float)(H - 1));
    float y1f = fminf(floorf(y), (float)(W - 1));
    float y2f = fminf(ceilf(y),  (float)(W - 1));
    float z1f = fminf(floorf(z), (float)(D - 1));
    float z2f = fminf(ceilf(z),  (float)(D - 1));

    int x1 = max(0, (int)x1f), x2 = max(0, (int)x2f);
    int y1 = max(0, (int)y1f), y2 = max(0, (int)y2f);
    int z1 = max(0, (int)z1f), z2 = max(0, (int)z2f);

    // weights exactly as reference (degenerate -> 0 when floor==ceil)
    float wx = x - x1f, wx2 = x2f - x;
    float wy = y - y1f, wy2 = y2f - y;
    float wz = z - z1f, wz2 = z2f - z;

    const float* base = img + (size_t)(b * C + c) * (size_t)(H * W * D);

    // 8 corner gathers
    size_t r11 = ((size_t)x1 * W + y1) * D;
    size_t r12 = ((size_t)x1 * W + y2) * D;
    size_t r21 = ((size_t)x2 * W + y1) * D;
    size_t r22 = ((size_t)x2 * W + y2) * D;

    float v_x1y1z1 = base[r11 + z1];
    float v_x1y1z2 = base[r11 + z2];
    float v_x1y2z1 = base[r12 + z1];
    float v_x1y2z2 = base[r12 + z2];
    float v_x2y1z1 = base[r21 + z1];
    float v_x2y1z2 = base[r21 + z2];
    float v_x2y2z1 = base[r22 + z1];
    float v_x2y2z2 = base[r22 + z2];

    // z = z2 plane (reference: lerp_y(z2)*wz + lerp_y(z1)*wz2)
    float lx1_a = v_x2y1z2 * wx + v_x1y1z2 * wx2;
    float lx2_a = v_x2y2z2 * wx + v_x1y2z2 * wx2;
    float ly_a  = lx2_a * wy + lx1_a * wy2;
    // z = z1 plane
    float lx1_b = v_x2y1z1 * wx + v_x1y1z1 * wx2;
    float lx2_b = v_x2y2z1 * wx + v_x1y2z1 * wx2;
    float ly_b  = lx2_b * wy + lx1_b * wy2;

    out[o] = ly_a * wz + ly_b * wz2;
}

extern "C" void kernel_launch(void* const* d_in, const int* in_sizes, int n_in,
                              void* d_out, int out_size, void* d_ws, size_t ws_size,
                              hipStream_t stream) {
    const float* img  = (const float*)d_in[0];  // image_features fp32
    const float* gf   = (const float*)d_in[1];  // graph_features fp32
    // d_in[2] = batch (int32) — numerically unused by the reference
    const int*   dimp = (const int*)d_in[3];    // image_dim scalar

    float* out = (float*)d_out;
    int total  = out_size;                       // NPER * B * C
    int blocks = (total + 255) / 256;
    og_proj_kernel<<<blocks, 256, 0, stream>>>(img, gf, dimp, out);
}

// Round 2
// 206.665 us; speedup vs baseline: 1.2985x; 1.2985x over previous
//
#include <hip/hip_runtime.h>
#include <hip/hip_fp16.h>

// Problem constants (match reference setup_inputs()).
constexpr int B = 4, C = 8, H = 160, W = 160, Dd = 160, NPER = 100000;
constexpr long HWD = (long)H * W * Dd;            // 4,096,000 voxels per image
constexpr int  TOTAL_PTS = NPER * B;              // 400,000 (point, image) pairs
constexpr int  TOTAL_OUT = NPER * B * C;          // 3,200,000 output elements
constexpr size_t WS_NEEDED = (size_t)B * HWD * C * sizeof(__half);  // 262,144,000 B

// ---------------------------------------------------------------------------
// Pass 1: [B,C,H,W,D] fp32  ->  [B, H*W*D, C] fp16 (channel-last), 4 voxels/thread.
// Reads: per channel, consecutive threads read consecutive float4 -> coalesced.
// Writes: each thread writes 64 B contiguous -> coalesced.
// ---------------------------------------------------------------------------
__global__ __launch_bounds__(256) void transpose_kernel(
    const float* __restrict__ img, __half* __restrict__ ws)
{
    long t = (long)blockIdx.x * 256 + threadIdx.x;     // voxel-quad id
    const long nquads = (long)B * HWD / 4;             // 4,096,000
    if (t >= nquads) return;

    long v0 = t * 4;                 // first voxel (global, incl. batch)
    long b  = v0 / HWD;
    long v  = v0 - b * HWD;          // voxel within image
    const float* base = img + b * C * HWD + v;

    float4 ch[8];
    #pragma unroll
    for (int c = 0; c < 8; ++c)
        ch[c] = *reinterpret_cast<const float4*>(base + (long)c * HWD);

    #pragma unroll
    for (int q = 0; q < 4; ++q) {
        __half h[8];
        #pragma unroll
        for (int c = 0; c < 8; ++c)
            h[c] = __float2half(reinterpret_cast<const float*>(&ch[c])[q]);
        *reinterpret_cast<float4*>(ws + (v0 + q) * 8) =
            *reinterpret_cast<const float4*>(h);
    }
}

// ---------------------------------------------------------------------------
// Pass 2: one thread per (point j, image b). 8 corners x 16 B fp16 loads,
// exact reference lerp nesting per channel, 32 B fp32 coalesced store.
// ---------------------------------------------------------------------------
__global__ __launch_bounds__(256) void gather_kernel(
    const __half* __restrict__ ws,   // [B, HWD, C] fp16
    const float*  __restrict__ gf,   // [B*NPER, 3]
    const int*    __restrict__ dimp, // [1] image_dim
    float*        __restrict__ out)  // [NPER, B*C]
{
    int t = blockIdx.x * 256 + threadIdx.x;
    if (t >= TOTAL_PTS) return;
    int j = t >> 2;                  // point index within image
    int b = t & 3;                   // image index

    int iv = dimp[0];
    float image_dim = (iv > 0 && iv < 1000000) ? (float)iv : __int_as_float(iv);
    float factor = image_dim / (float)H;

    long p = (long)b * NPER + j;
    float x = gf[p * 3 + 0] / factor;
    float y = gf[p * 3 + 1] / factor;
    float z = gf[p * 3 + 2] / factor;

    float x1f = fminf(floorf(x), (float)(H - 1));
    float x2f = fminf(ceilf(x),  (float)(H - 1));
    float y1f = fminf(floorf(y), (float)(W - 1));
    float y2f = fminf(ceilf(y),  (float)(W - 1));
    float z1f = fminf(floorf(z), (float)(Dd - 1));
    float z2f = fminf(ceilf(z),  (float)(Dd - 1));

    int x1 = max(0, (int)x1f), x2 = max(0, (int)x2f);
    int y1 = max(0, (int)y1f), y2 = max(0, (int)y2f);
    int z1 = max(0, (int)z1f), z2 = max(0, (int)z2f);

    float wx = x - x1f, wx2 = x2f - x;
    float wy = y - y1f, wy2 = y2f - y;
    float wz = z - z1f, wz2 = z2f - z;

    const __half* base = ws + (long)b * HWD * 8;

    auto corner = [&](int xi, int yi, int zi, float* v) {
        long vox = ((long)xi * W + yi) * Dd + zi;
        float4 raw = *reinterpret_cast<const float4*>(base + vox * 8);
        const __half* h = reinterpret_cast<const __half*>(&raw);
        #pragma unroll
        for (int c = 0; c < 8; ++c) v[c] = __half2float(h[c]);
    };

    float a11[8], a12[8], a21[8], a22[8];
    float ly_a[8], ly_b[8];

    // z = z2 plane
    corner(x1, y1, z2, a11);
    corner(x1, y2, z2, a12);
    corner(x2, y1, z2, a21);
    corner(x2, y2, z2, a22);
    #pragma unroll
    for (int c = 0; c < 8; ++c) {
        float lx1 = a21[c] * wx + a11[c] * wx2;
        float lx2 = a22[c] * wx + a12[c] * wx2;
        ly_a[c] = lx2 * wy + lx1 * wy2;
    }
    // z = z1 plane
    corner(x1, y1, z1, a11);
    corner(x1, y2, z1, a12);
    corner(x2, y1, z1, a21);
    corner(x2, y2, z1, a22);
    #pragma unroll
    for (int c = 0; c < 8; ++c) {
        float lx1 = a21[c] * wx + a11[c] * wx2;
        float lx2 = a22[c] * wx + a12[c] * wx2;
        ly_b[c] = lx2 * wy + lx1 * wy2;
    }

    float res[8];
    #pragma unroll
    for (int c = 0; c < 8; ++c) res[c] = ly_a[c] * wz + ly_b[c] * wz2;

    // out row j, columns b*8 .. b*8+7 — 32 B contiguous, coalesced across wave
    float* dst = out + (long)j * 32 + b * 8;
    *reinterpret_cast<float4*>(dst)     = *reinterpret_cast<const float4*>(&res[0]);
    *reinterpret_cast<float4*>(dst + 4) = *reinterpret_cast<const float4*>(&res[4]);
}

// ---------------------------------------------------------------------------
// Fallback: direct gather on the original layout (round-1 kernel), used only
// if ws_size is unexpectedly too small for the channel-last copy.
// ---------------------------------------------------------------------------
__global__ __launch_bounds__(256) void og_proj_direct(
    const float* __restrict__ img, const float* __restrict__ gf,
    const int* __restrict__ dimp, float* __restrict__ out)
{
    int o = blockIdx.x * 256 + threadIdx.x;
    if (o >= TOTAL_OUT) return;
    int j = o >> 5, bc = o & 31, b = bc >> 3, c = bc & 7;

    int iv = dimp[0];
    float image_dim = (iv > 0 && iv < 1000000) ? (float)iv : __int_as_float(iv);
    float factor = image_dim / (float)H;

    long p = (long)b * NPER + j;
    float x = gf[p * 3 + 0] / factor;
    float y = gf[p * 3 + 1] / factor;
    float z = gf[p * 3 + 2] / factor;

    float x1f = fminf(floorf(x), (float)(H - 1));
    float x2f = fminf(ceilf(x),  (float)(H - 1));
    float y1f = fminf(floorf(y), (float)(W - 1));
    float y2f = fminf(ceilf(y),  (float)(W - 1));
    float z1f = fminf(floorf(z), (float)(Dd - 1));
    float z2f = fminf(ceilf(z),  (float)(Dd - 1));
    int x1 = max(0, (int)x1f), x2 = max(0, (int)x2f);
    int y1 = max(0, (int)y1f), y2 = max(0, (int)y2f);
    int z1 = max(0, (int)z1f), z2 = max(0, (int)z2f);
    float wx = x - x1f, wx2 = x2f - x;
    float wy = y - y1f, wy2 = y2f - y;
    float wz = z - z1f, wz2 = z2f - z;

    const float* base = img + (size_t)(b * C + c) * (size_t)HWD;
    size_t r11 = ((size_t)x1 * W + y1) * Dd;
    size_t r12 = ((size_t)x1 * W + y2) * Dd;
    size_t r21 = ((size_t)x2 * W + y1) * Dd;
    size_t r22 = ((size_t)x2 * W + y2) * Dd;

    float lx1_a = base[r21 + z2] * wx + base[r11 + z2] * wx2;
    float lx2_a = base[r22 + z2] * wx + base[r12 + z2] * wx2;
    float ly_a  = lx2_a * wy + lx1_a * wy2;
    float lx1_b = base[r21 + z1] * wx + base[r11 + z1] * wx2;
    float lx2_b = base[r22 + z1] * wx + base[r12 + z1] * wx2;
    float ly_b  = lx2_b * wy + lx1_b * wy2;
    out[o] = ly_a * wz + ly_b * wz2;
}

extern "C" void kernel_launch(void* const* d_in, const int* in_sizes, int n_in,
                              void* d_out, int out_size, void* d_ws, size_t ws_size,
                              hipStream_t stream) {
    const float* img  = (const float*)d_in[0];
    const float* gf   = (const float*)d_in[1];
    const int*   dimp = (const int*)d_in[3];
    float* out = (float*)d_out;

    if (ws_size >= WS_NEEDED) {
        __half* ws = (__half*)d_ws;
        long nquads = (long)B * HWD / 4;                 // 4,096,000
        int tblocks = (int)((nquads + 255) / 256);       // 16,000
        transpose_kernel<<<tblocks, 256, 0, stream>>>(img, ws);
        int gblocks = (TOTAL_PTS + 255) / 256;           // 1,563
        gather_kernel<<<gblocks, 256, 0, stream>>>(ws, gf, dimp, out);
    } else {
        int blocks = (TOTAL_OUT + 255) / 256;
        og_proj_direct<<<blocks, 256, 0, stream>>>(img, gf, dimp, out);
    }
}